// Round 2
// baseline (2177.195 us; speedup 1.0000x reference)
//
#include <hip/hip_runtime.h>
#include <hip/hip_bf16.h>
#include <stdint.h>

// Problem constants (from reference)
#define N_NODES 50000
#define R_REL   4
#define E_EDGES 150000
#define DIM     128
#define K_TOT   512         // R * DIM
#define M_PAD   50048       // 391 * 128  (ceil(N/128)*128)
#define BM      128
#define BK      64

typedef __attribute__((ext_vector_type(4))) float f32x4;
typedef __attribute__((ext_vector_type(8))) short short8;

__device__ __forceinline__ short f2bf(float f) {
    union { float f; unsigned u; } x{f};
    unsigned r = (x.u + 0x7fffu + ((x.u >> 16) & 1u)) >> 16;
    return (short)r;
}

// ---------------- degree counting ----------------
__global__ void count_deg(const int* __restrict__ src, const int* __restrict__ dst,
                          float* __restrict__ deg_out, float* __restrict__ deg_in) {
    int i = blockIdx.x * blockDim.x + threadIdx.x;
    if (i >= R_REL * E_EDGES) return;
    int r = i / E_EDGES;
    unsafeAtomicAdd(&deg_out[r * N_NODES + src[i]], 1.0f);
    unsafeAtomicAdd(&deg_in [r * N_NODES + dst[i]], 1.0f);
}

__global__ void finalize_deg(float* __restrict__ p, int n) {
    int i = blockIdx.x * blockDim.x + threadIdx.x;
    if (i < n) p[i] = rsqrtf(fmaxf(p[i], 1.0f));
}

// ---------------- weight prep: transpose+cvt W[r][d][o] -> Wt[o][r*128+d] (bf16), bias[o]=sum_r b[r][o]
__global__ void prep_w(const float* __restrict__ W, const float* __restrict__ b,
                       short* __restrict__ Wt, float* __restrict__ bias) {
    int i = blockIdx.x * blockDim.x + threadIdx.x;
    if (i < DIM * K_TOT) {
        int o = i / K_TOT, k = i % K_TOT;      // k = r*128 + d
        Wt[i] = f2bf(W[(size_t)k * DIM + o]);  // W flat: (r*128+d)*128 + o
    }
    if (i < DIM) {
        float s = 0.f;
        for (int r = 0; r < R_REL; ++r) s += b[r * DIM + i];
        bias[i] = s;
    }
}

// ---------------- edge scatter: agg[dst][r*128+d] += w * h[src][d]
__global__ void scatter_edges(const int* __restrict__ src, const int* __restrict__ dst,
                              const float* __restrict__ rs_out, const float* __restrict__ rs_in,
                              const float* __restrict__ h, float* __restrict__ agg) {
    int t = blockIdx.x * blockDim.x + threadIdx.x;
    int e = t >> 5;            // 32 threads per edge
    if (e >= R_REL * E_EDGES) return;
    int lane = t & 31;
    int r = e / E_EDGES;
    int s = src[e], d = dst[e];
    float w = rs_out[r * N_NODES + s] * rs_in[r * N_NODES + d];
    f32x4 v = *((const f32x4*)(h + (size_t)s * DIM) + lane);
    float* o = agg + (size_t)d * K_TOT + r * DIM + lane * 4;
    unsafeAtomicAdd(o + 0, v[0] * w);
    unsafeAtomicAdd(o + 1, v[1] * w);
    unsafeAtomicAdd(o + 2, v[2] * w);
    unsafeAtomicAdd(o + 3, v[3] * w);
}

// ---------------- GEMM: out[M,128] = A[M,512](f32->bf16) @ Wt^T + bias, optional relu
// Wt stored as [128 cols][512 k] bf16 (pre-transposed) so B-fragments read contiguous k.
template <bool RELU>
__global__ __launch_bounds__(256, 2)
void gemm_kernel(const float* __restrict__ A, const short* __restrict__ Wt,
                 const float* __restrict__ bias, float* __restrict__ out) {
    __shared__ short a_sh[128 * 72];   // [row][k], padded stride 72 (bank-safe)
    __shared__ short b_sh[128 * 72];   // [col][k], padded stride 72

    const int tid  = threadIdx.x;
    const int bm0  = blockIdx.x * BM;
    const int lane = tid & 63;
    const int wid  = tid >> 6;
    const int wm   = wid >> 1, wn = wid & 1;   // 2x2 waves of 64x64
    const int l15  = lane & 15, l4 = lane >> 4;

    f32x4 acc[4][4] = {};

    for (int kk = 0; kk < K_TOT; kk += BK) {
        __syncthreads();
        // stage A tile: 128 rows x 64 k (f32 -> bf16); 1024 short8 writes
#pragma unroll
        for (int j = 0; j < 4; ++j) {
            int c = tid + 256 * j;
            int row = c >> 3, ku = c & 7;
            const float* g = A + (size_t)(bm0 + row) * K_TOT + kk + ku * 8;
            f32x4 v0 = *(const f32x4*)g;
            f32x4 v1 = *(const f32x4*)(g + 4);
            short8 sv;
            sv[0] = f2bf(v0[0]); sv[1] = f2bf(v0[1]); sv[2] = f2bf(v0[2]); sv[3] = f2bf(v0[3]);
            sv[4] = f2bf(v1[0]); sv[5] = f2bf(v1[1]); sv[6] = f2bf(v1[2]); sv[7] = f2bf(v1[3]);
            *(short8*)&a_sh[row * 72 + ku * 8] = sv;
        }
        // stage B tile: 128 cols x 64 k (already bf16); 1024 short8 writes
        // (round-1 bug: only half the tile was staged -> uninit LDS -> NaN)
#pragma unroll
        for (int j = 0; j < 4; ++j) {
            int c = tid + 256 * j;
            int col = c >> 3, ku = c & 7;
            *(short8*)&b_sh[col * 72 + ku * 8] =
                *(const short8*)(Wt + (size_t)col * K_TOT + kk + ku * 8);
        }
        __syncthreads();
#pragma unroll
        for (int ki = 0; ki < 2; ++ki) {
            short8 a[4], b[4];
            int ku = ki * 4 + l4;
#pragma unroll
            for (int f = 0; f < 4; ++f) {
                int row = wm * 64 + f * 16 + l15;
                a[f] = *(const short8*)&a_sh[row * 72 + ku * 8];
                int col = wn * 64 + f * 16 + l15;
                b[f] = *(const short8*)&b_sh[col * 72 + ku * 8];
            }
#pragma unroll
            for (int fm = 0; fm < 4; ++fm)
#pragma unroll
                for (int fn = 0; fn < 4; ++fn)
                    acc[fm][fn] = __builtin_amdgcn_mfma_f32_16x16x32_bf16(
                        a[fm], b[fn], acc[fm][fn], 0, 0, 0);
        }
    }

    // epilogue: D mapping col = lane&15, row = (lane>>4)*4 + reg
#pragma unroll
    for (int fn = 0; fn < 4; ++fn) {
        int col = wn * 64 + fn * 16 + l15;
        float bi = bias[col];
#pragma unroll
        for (int fm = 0; fm < 4; ++fm) {
            int row0 = bm0 + wm * 64 + fm * 16 + l4 * 4;
#pragma unroll
            for (int rr = 0; rr < 4; ++rr) {
                int row = row0 + rr;
                if (row < N_NODES) {
                    float v = acc[fm][fn][rr] + bi;
                    if (RELU) v = fmaxf(v, 0.f);
                    out[(size_t)row * DIM + col] = v;
                }
            }
        }
    }
}

// ---------------- launcher ----------------
extern "C" void kernel_launch(void* const* d_in, const int* in_sizes, int n_in,
                              void* d_out, int out_size, void* d_ws, size_t ws_size,
                              hipStream_t stream) {
    const float* x    = (const float*)d_in[0];
    const int*   esrc = (const int*)  d_in[1];
    const int*   edst = (const int*)  d_in[2];
    const float* W1   = (const float*)d_in[3];
    const float* b1   = (const float*)d_in[4];
    const float* W2   = (const float*)d_in[5];
    const float* b2   = (const float*)d_in[6];
    float* out = (float*)d_out;
    char*  ws  = (char*)d_ws;

    // workspace layout (bytes):
    //   0        : rs_out  [R*N] f32   (800,000)
    //   800000   : rs_in   [R*N] f32   (800,000)
    //   1600000  : bias1   [128] f32
    //   1600512  : bias2   [128] f32
    //   1601024  : Wt1     [128][512] bf16 (131,072)
    //   1732096  : Wt2     [128][512] bf16 (131,072)
    //   1863168  : h       [N][128] f32   (25,600,000)
    //   27463168 : agg     [M_PAD][512] f32 (102,498,304)
    // total ~130 MB
    float* rs     = (float*)ws;
    float* rs_out = rs;
    float* rs_in  = rs + R_REL * N_NODES;
    float* bias1  = (float*)(ws + 1600000);
    float* bias2  = (float*)(ws + 1600512);
    short* Wt1    = (short*)(ws + 1601024);
    short* Wt2    = (short*)(ws + 1732096);
    float* h      = (float*)(ws + 1863168);
    float* agg    = (float*)(ws + 27463168);

    // degrees -> rsqrt norms (computed once; valid for both layers)
    hipMemsetAsync(rs, 0, (size_t)2 * R_REL * N_NODES * sizeof(float), stream);
    count_deg<<<(R_REL * E_EDGES + 255) / 256, 256, 0, stream>>>(esrc, edst, rs_out, rs_in);
    finalize_deg<<<(2 * R_REL * N_NODES + 255) / 256, 256, 0, stream>>>(rs, 2 * R_REL * N_NODES);

    // weight prep
    prep_w<<<(DIM * K_TOT + 255) / 256, 256, 0, stream>>>(W1, b1, Wt1, bias1);
    prep_w<<<(DIM * K_TOT + 255) / 256, 256, 0, stream>>>(W2, b2, Wt2, bias2);

    const int scat_blocks = (R_REL * E_EDGES * 32) / 256;
    const int gemm_blocks = M_PAD / BM;

    // ---- layer 1 ----
    hipMemsetAsync(agg, 0, (size_t)M_PAD * K_TOT * sizeof(float), stream);
    scatter_edges<<<scat_blocks, 256, 0, stream>>>(esrc, edst, rs_out, rs_in, x, agg);
    gemm_kernel<true><<<gemm_blocks, 256, 0, stream>>>(agg, Wt1, bias1, h);

    // ---- layer 2 ----
    hipMemsetAsync(agg, 0, (size_t)M_PAD * K_TOT * sizeof(float), stream);
    scatter_edges<<<scat_blocks, 256, 0, stream>>>(esrc, edst, rs_out, rs_in, h, agg);
    gemm_kernel<false><<<gemm_blocks, 256, 0, stream>>>(agg, Wt2, bias2, out);
}

// Round 3
// 306.292 us; speedup vs baseline: 7.1082x; 7.1082x over previous
//
#include <hip/hip_runtime.h>
#include <hip/hip_bf16.h>
#include <stdint.h>

// Problem constants (from reference)
#define N_NODES 50000
#define R_REL   4
#define E_EDGES 150000
#define E_TOT   600000      // R * E
#define DIM     128
#define K_TOT   512         // R * DIM
#define M_PAD   50048       // 391 * 128  (ceil(N/128)*128)
#define NB      200000      // N * R buckets
#define BM      128
#define BK      64

typedef __attribute__((ext_vector_type(4))) float f32x4;
typedef __attribute__((ext_vector_type(8))) short short8;
typedef __attribute__((ext_vector_type(4))) short s16x4;

__device__ __forceinline__ short f2bf(float f) {
    union { float f; unsigned u; } x{f};
    unsigned r = (x.u + 0x7fffu + ((x.u >> 16) & 1u)) >> 16;
    return (short)r;
}

// ---------------- degree counting + dst-bucket histogram ----------------
__global__ void count_deg(const int* __restrict__ src, const int* __restrict__ dst,
                          float* __restrict__ deg_out, float* __restrict__ deg_in,
                          int* __restrict__ cnt) {
    int i = blockIdx.x * blockDim.x + threadIdx.x;
    if (i >= E_TOT) return;
    int r = i / E_EDGES;
    int s = src[i], d = dst[i];
    unsafeAtomicAdd(&deg_out[r * N_NODES + s], 1.0f);
    unsafeAtomicAdd(&deg_in [r * N_NODES + d], 1.0f);
    atomicAdd(&cnt[d * 4 + r], 1);
}

__global__ void finalize_deg(float* __restrict__ p, int n) {
    int i = blockIdx.x * blockDim.x + threadIdx.x;
    if (i < n) p[i] = rsqrtf(fmaxf(p[i], 1.0f));
}

// ---------------- prefix sum (3 kernels) ----------------
// scan1: per-block (256) exclusive scan of cnt -> row_ptr, block sums -> partials
__global__ void scan1(const int* __restrict__ cnt, int* __restrict__ row_ptr,
                      int* __restrict__ partials) {
    __shared__ int sh[256];
    int tid = threadIdx.x;
    int i = blockIdx.x * 256 + tid;
    int v = (i < NB) ? cnt[i] : 0;
    sh[tid] = v;
    __syncthreads();
#pragma unroll
    for (int off = 1; off < 256; off <<= 1) {
        int t2 = (tid >= off) ? sh[tid - off] : 0;
        __syncthreads();
        sh[tid] += t2;
        __syncthreads();
    }
    if (i < NB) row_ptr[i] = sh[tid] - v;      // exclusive
    if (tid == 255) partials[blockIdx.x] = sh[255];
}

// scan2: single block exclusive scan of partials (nb <= 1024)
__global__ void scan2(int* __restrict__ partials, int nb) {
    __shared__ int sh[1024];
    int tid = threadIdx.x;
    int v = (tid < nb) ? partials[tid] : 0;
    sh[tid] = v;
    __syncthreads();
    for (int off = 1; off < 1024; off <<= 1) {
        int t2 = (tid >= off) ? sh[tid - off] : 0;
        __syncthreads();
        sh[tid] += t2;
        __syncthreads();
    }
    if (tid < nb) partials[tid] = sh[tid] - v;  // exclusive
}

// scan3: add block offsets; set terminator
__global__ void scan3(int* __restrict__ row_ptr, const int* __restrict__ partials) {
    int i = blockIdx.x * 256 + threadIdx.x;
    if (i < NB) row_ptr[i] += partials[i >> 8];
    if (i == 0) row_ptr[NB] = E_TOT;
}

// ---------------- fill CSR edge records {src, rs_out[r][src]} ----------------
__global__ void fill_csr(const int* __restrict__ src, const int* __restrict__ dst,
                         const int* __restrict__ row_ptr, int* __restrict__ cursor,
                         const float* __restrict__ rs_out, int2* __restrict__ erec) {
    int i = blockIdx.x * blockDim.x + threadIdx.x;
    if (i >= E_TOT) return;
    int r = i / E_EDGES;
    int s = src[i], d = dst[i];
    int b = d * 4 + r;
    int pos = row_ptr[b] + atomicAdd(&cursor[b], 1);
    int2 rec;
    rec.x = s;
    rec.y = __float_as_int(rs_out[r * N_NODES + s]);
    erec[pos] = rec;
}

// ---------------- weight prep: transpose+cvt W[r][d][o] -> Wt[o][r*128+d] (bf16)
__global__ void prep_w(const float* __restrict__ W, const float* __restrict__ b,
                       short* __restrict__ Wt, float* __restrict__ bias) {
    int i = blockIdx.x * blockDim.x + threadIdx.x;
    if (i < DIM * K_TOT) {
        int o = i / K_TOT, k = i % K_TOT;      // k = r*128 + d
        Wt[i] = f2bf(W[(size_t)k * DIM + o]);  // W flat: (r*128+d)*128 + o
    }
    if (i < DIM) {
        float s = 0.f;
        for (int r = 0; r < R_REL; ++r) s += b[r * DIM + i];
        bias[i] = s;
    }
}

// ---------------- gather: agg[dst][r*128 + :] = rs_in * sum_e w_e * h[src_e][:]  (bf16 out)
__global__ void gather_edges(const int* __restrict__ row_ptr, const int2* __restrict__ erec,
                             const float* __restrict__ rs_in, const float* __restrict__ h,
                             short* __restrict__ agg) {
    int t = blockIdx.x * blockDim.x + threadIdx.x;
    int pair = t >> 5;               // 32 lanes per (dst, r) pair
    if (pair >= NB) return;
    int lane = t & 31;
    int d = pair >> 2, r = pair & 3;
    int beg = row_ptr[pair], end = row_ptr[pair + 1];
    f32x4 acc = {0.f, 0.f, 0.f, 0.f};
    for (int e = beg; e < end; ++e) {
        int2 rec = erec[e];
        float w = __int_as_float(rec.y);
        f32x4 v = *((const f32x4*)(h + (size_t)rec.x * DIM) + lane);
        acc += v * w;
    }
    acc *= rs_in[r * N_NODES + d];
    s16x4 o;
    o[0] = f2bf(acc[0]); o[1] = f2bf(acc[1]); o[2] = f2bf(acc[2]); o[3] = f2bf(acc[3]);
    *((s16x4*)(agg + (size_t)d * K_TOT + r * DIM) + lane) = o;
}

// ---------------- GEMM: out[M,128] = A[M,512](bf16) @ Wt^T + bias, optional relu
template <bool RELU>
__global__ __launch_bounds__(256, 2)
void gemm_kernel(const short* __restrict__ A, const short* __restrict__ Wt,
                 const float* __restrict__ bias, float* __restrict__ out) {
    __shared__ short a_sh[128 * 72];   // [row][k], padded stride 72
    __shared__ short b_sh[128 * 72];   // [col][k], padded stride 72

    const int tid  = threadIdx.x;
    const int bm0  = blockIdx.x * BM;
    const int lane = tid & 63;
    const int wid  = tid >> 6;
    const int wm   = wid >> 1, wn = wid & 1;   // 2x2 waves of 64x64
    const int l15  = lane & 15, l4 = lane >> 4;

    f32x4 acc[4][4] = {};

    for (int kk = 0; kk < K_TOT; kk += BK) {
        __syncthreads();
        // stage A tile: 128 rows x 64 k bf16 (1024 short8 writes)
#pragma unroll
        for (int j = 0; j < 4; ++j) {
            int c = tid + 256 * j;
            int row = c >> 3, ku = c & 7;
            *(short8*)&a_sh[row * 72 + ku * 8] =
                *(const short8*)(A + (size_t)(bm0 + row) * K_TOT + kk + ku * 8);
        }
        // stage B tile: 128 cols x 64 k (1024 short8 writes)
#pragma unroll
        for (int j = 0; j < 4; ++j) {
            int c = tid + 256 * j;
            int col = c >> 3, ku = c & 7;
            *(short8*)&b_sh[col * 72 + ku * 8] =
                *(const short8*)(Wt + (size_t)col * K_TOT + kk + ku * 8);
        }
        __syncthreads();
#pragma unroll
        for (int ki = 0; ki < 2; ++ki) {
            short8 a[4], b[4];
            int ku = ki * 4 + l4;
#pragma unroll
            for (int f = 0; f < 4; ++f) {
                int row = wm * 64 + f * 16 + l15;
                a[f] = *(const short8*)&a_sh[row * 72 + ku * 8];
                int col = wn * 64 + f * 16 + l15;
                b[f] = *(const short8*)&b_sh[col * 72 + ku * 8];
            }
#pragma unroll
            for (int fm = 0; fm < 4; ++fm)
#pragma unroll
                for (int fn = 0; fn < 4; ++fn)
                    acc[fm][fn] = __builtin_amdgcn_mfma_f32_16x16x32_bf16(
                        a[fm], b[fn], acc[fm][fn], 0, 0, 0);
        }
    }

    // epilogue: D mapping col = lane&15, row = (lane>>4)*4 + reg
#pragma unroll
    for (int fn = 0; fn < 4; ++fn) {
        int col = wn * 64 + fn * 16 + l15;
        float bi = bias[col];
#pragma unroll
        for (int fm = 0; fm < 4; ++fm) {
            int row0 = bm0 + wm * 64 + fm * 16 + l4 * 4;
#pragma unroll
            for (int rr = 0; rr < 4; ++rr) {
                int row = row0 + rr;
                if (row < N_NODES) {
                    float v = acc[fm][fn][rr] + bi;
                    if (RELU) v = fmaxf(v, 0.f);
                    out[(size_t)row * DIM + col] = v;
                }
            }
        }
    }
}

// ---------------- launcher ----------------
extern "C" void kernel_launch(void* const* d_in, const int* in_sizes, int n_in,
                              void* d_out, int out_size, void* d_ws, size_t ws_size,
                              hipStream_t stream) {
    const float* x    = (const float*)d_in[0];
    const int*   esrc = (const int*)  d_in[1];
    const int*   edst = (const int*)  d_in[2];
    const float* W1   = (const float*)d_in[3];
    const float* b1   = (const float*)d_in[4];
    const float* W2   = (const float*)d_in[5];
    const float* b2   = (const float*)d_in[6];
    float* out = (float*)d_out;
    char*  ws  = (char*)d_ws;

    // workspace layout (bytes), ~86 MB total:
    float* rs     = (float*)ws;                    // rs_out + rs_in, 2*800,000
    float* rs_out = rs;
    float* rs_in  = rs + R_REL * N_NODES;
    float* bias1  = (float*)(ws + 1600000);        // 512
    float* bias2  = (float*)(ws + 1600512);        // 512
    short* Wt1    = (short*)(ws + 1601024);        // 131,072
    short* Wt2    = (short*)(ws + 1732096);        // 131,072 -> 1,863,168
    float* h      = (float*)(ws + 1863168);        // 25,600,000 -> 27,463,168
    short* agg    = (short*)(ws + 27463168);       // M_PAD*512*2 = 51,249,152 -> 78,712,320
    int*   cnt    = (int*)  (ws + 78712320);       // 800,000 -> 79,512,320
    int*   cursor = (int*)  (ws + 79512320);       // 800,000 -> 80,312,320
    int*   rowptr = (int*)  (ws + 80312320);       // 800,064 -> 81,112,384
    int*   parts  = (int*)  (ws + 81112384);       // 4,096   -> 81,116,480
    int2*  erec   = (int2*) (ws + 81116544);       // 4,800,000 -> 85,916,544

    // zero degree + histogram + cursor buffers
    hipMemsetAsync(rs, 0, (size_t)2 * R_REL * N_NODES * sizeof(float), stream);
    hipMemsetAsync(cnt, 0, 2 * 800000, stream);    // cnt + cursor (contiguous)

    count_deg<<<(E_TOT + 255) / 256, 256, 0, stream>>>(esrc, edst, rs_out, rs_in, cnt);
    finalize_deg<<<(2 * R_REL * N_NODES + 255) / 256, 256, 0, stream>>>(rs, 2 * R_REL * N_NODES);

    // prefix sum: 782 blocks of 256
    const int nb_blk = (NB + 255) / 256;           // 782
    scan1<<<nb_blk, 256, 0, stream>>>(cnt, rowptr, parts);
    scan2<<<1, 1024, 0, stream>>>(parts, nb_blk);
    scan3<<<nb_blk, 256, 0, stream>>>(rowptr, parts);

    fill_csr<<<(E_TOT + 255) / 256, 256, 0, stream>>>(esrc, edst, rowptr, cursor, rs_out, erec);

    prep_w<<<(DIM * K_TOT + 255) / 256, 256, 0, stream>>>(W1, b1, Wt1, bias1);
    prep_w<<<(DIM * K_TOT + 255) / 256, 256, 0, stream>>>(W2, b2, Wt2, bias2);

    const int gat_blocks = (NB * 32) / 256;        // 25,000
    const int gemm_blocks = M_PAD / BM;            // 391

    // ---- layer 1 ----
    gather_edges<<<gat_blocks, 256, 0, stream>>>(rowptr, erec, rs_in, x, agg);
    gemm_kernel<true><<<gemm_blocks, 256, 0, stream>>>(agg, Wt1, bias1, h);

    // ---- layer 2 ----
    gather_edges<<<gat_blocks, 256, 0, stream>>>(rowptr, erec, rs_in, h, agg);
    gemm_kernel<false><<<gemm_blocks, 256, 0, stream>>>(agg, Wt2, bias2, out);
}

// Round 4
// 264.382 us; speedup vs baseline: 8.2350x; 1.1585x over previous
//
#include <hip/hip_runtime.h>
#include <hip/hip_bf16.h>
#include <stdint.h>

// Problem constants (from reference)
#define N_NODES 50000
#define R_REL   4
#define E_EDGES 150000
#define E_TOT   600000      // R * E
#define DIM     128
#define K_TOT   512         // R * DIM
#define M_PAD   50048       // 391 * 128  (ceil(N/128)*128)
#define NB      200000      // N * R buckets
#define NC      8           // histogram privatization copies (~per-XCD)
#define BM      128
#define BK      64

typedef __attribute__((ext_vector_type(4))) float f32x4;
typedef __attribute__((ext_vector_type(8))) short short8;
typedef __attribute__((ext_vector_type(4))) short s16x4;

__device__ __forceinline__ short f2bf(float f) {
    union { float f; unsigned u; } x{f};
    unsigned r = (x.u + 0x7fffu + ((x.u >> 16) & 1u)) >> 16;
    return (short)r;
}
__device__ __forceinline__ float bf2f(short s) {
    union { unsigned u; float f; } x;
    x.u = ((unsigned)(unsigned short)s) << 16;
    return x.f;
}

// ---------------- edge histograms (privatized 8-way by blockIdx&7 ~ XCD) ----
__global__ void hist_edges(const int* __restrict__ src, const int* __restrict__ dst,
                           int* __restrict__ cnt_src, int* __restrict__ cnt_dst) {
    int i = blockIdx.x * 256 + threadIdx.x;
    if (i >= E_TOT) return;
    int c = blockIdx.x & (NC - 1);
    int r = i / E_EDGES;
    atomicAdd(&cnt_src[c * NB + src[i] * 4 + r], 1);
    atomicAdd(&cnt_dst[c * NB + dst[i] * 4 + r], 1);
}

// ---------------- degrees -> rsqrt norms (sums the 8 copies) ----------------
__global__ void finalize_deg(const int* __restrict__ cnt_src, const int* __restrict__ cnt_dst,
                             float* __restrict__ rs_out, float* __restrict__ rs_in) {
    int b = blockIdx.x * 256 + threadIdx.x;     // bucket = node*4 + r
    if (b >= NB) return;
    int s1 = 0, s2 = 0;
#pragma unroll
    for (int c = 0; c < NC; ++c) { s1 += cnt_src[c * NB + b]; s2 += cnt_dst[c * NB + b]; }
    int node = b >> 2, r = b & 3;
    rs_out[r * N_NODES + node] = rsqrtf(fmaxf((float)s1, 1.0f));
    rs_in [r * N_NODES + node] = rsqrtf(fmaxf((float)s2, 1.0f));
}

// ---------------- prefix sum over bucket totals (3 kernels) ----------------
__global__ void scan1(const int* __restrict__ cnt_dst, int* __restrict__ row_ptr,
                      int* __restrict__ partials) {
    __shared__ int sh[256];
    int tid = threadIdx.x;
    int i = blockIdx.x * 256 + tid;
    int v = 0;
    if (i < NB) {
#pragma unroll
        for (int c = 0; c < NC; ++c) v += cnt_dst[c * NB + i];
    }
    sh[tid] = v;
    __syncthreads();
#pragma unroll
    for (int off = 1; off < 256; off <<= 1) {
        int t2 = (tid >= off) ? sh[tid - off] : 0;
        __syncthreads();
        sh[tid] += t2;
        __syncthreads();
    }
    if (i < NB) row_ptr[i] = sh[tid] - v;      // exclusive
    if (tid == 255) partials[blockIdx.x] = sh[255];
}

__global__ void scan2(int* __restrict__ partials, int nb) {
    __shared__ int sh[1024];
    int tid = threadIdx.x;
    int v = (tid < nb) ? partials[tid] : 0;
    sh[tid] = v;
    __syncthreads();
    for (int off = 1; off < 1024; off <<= 1) {
        int t2 = (tid >= off) ? sh[tid - off] : 0;
        __syncthreads();
        sh[tid] += t2;
        __syncthreads();
    }
    if (tid < nb) partials[tid] = sh[tid] - v;  // exclusive
}

// scan3: add block offsets; convert per-copy counts -> per-copy exclusive bases
// (in place: cnt_dst[c][b] becomes base of copy c within bucket b; fill's
// atomicAdd on it then serves as base+cursor combined)
__global__ void scan3(int* __restrict__ row_ptr, const int* __restrict__ partials,
                      int* __restrict__ cnt_dst) {
    int i = blockIdx.x * 256 + threadIdx.x;
    if (i < NB) {
        row_ptr[i] += partials[i >> 8];
        int run = 0;
#pragma unroll
        for (int c = 0; c < NC; ++c) {
            int v = cnt_dst[c * NB + i];
            cnt_dst[c * NB + i] = run;
            run += v;
        }
    }
    if (i == 0) row_ptr[NB] = E_TOT;
}

// ---------------- fill CSR edge records {src, rs_out[r][src]} ----------------
__global__ void fill_csr(const int* __restrict__ src, const int* __restrict__ dst,
                         const int* __restrict__ row_ptr, int* __restrict__ base_cur,
                         const float* __restrict__ rs_out, int2* __restrict__ erec) {
    int i = blockIdx.x * 256 + threadIdx.x;
    if (i >= E_TOT) return;
    int c = blockIdx.x & (NC - 1);              // same mapping as hist_edges
    int r = i / E_EDGES;
    int s = src[i], d = dst[i];
    int b = d * 4 + r;
    int pos = row_ptr[b] + atomicAdd(&base_cur[c * NB + b], 1);
    int2 rec;
    rec.x = s;
    rec.y = __float_as_int(rs_out[r * N_NODES + s]);
    erec[pos] = rec;
}

// ---------------- weight prep (both layers in one launch) -------------------
__global__ void prep_w(const float* __restrict__ W1, const float* __restrict__ b1,
                       const float* __restrict__ W2, const float* __restrict__ b2,
                       short* __restrict__ Wt1, short* __restrict__ Wt2,
                       float* __restrict__ bias1, float* __restrict__ bias2) {
    int i = blockIdx.x * 256 + threadIdx.x;     // grid covers 2*DIM*K_TOT
    int layer = i >= DIM * K_TOT;
    int j = i - layer * DIM * K_TOT;
    const float* W = layer ? W2 : W1;
    short* Wt = layer ? Wt2 : Wt1;
    int o = j / K_TOT, k = j % K_TOT;           // k = r*128 + d
    Wt[j] = f2bf(W[(size_t)k * DIM + o]);
    if (j < DIM) {
        const float* b = layer ? b2 : b1;
        float* bias = layer ? bias2 : bias1;
        float s = 0.f;
        for (int r = 0; r < R_REL; ++r) s += b[r * DIM + j];
        bias[j] = s;
    }
}

// ---------------- gather: agg[d][r*128+:] = rs_in * sum_e w_e * h[src_e][:] (bf16 out)
template <typename T>
__global__ void gather_edges(const int* __restrict__ row_ptr, const int2* __restrict__ erec,
                             const float* __restrict__ rs_in, const T* __restrict__ h,
                             short* __restrict__ agg) {
    int t = blockIdx.x * blockDim.x + threadIdx.x;
    int pair = t >> 5;               // 32 lanes per (dst, r) pair
    if (pair >= NB) return;
    int lane = t & 31;
    int d = pair >> 2, r = pair & 3;
    int beg = row_ptr[pair], end = row_ptr[pair + 1];
    f32x4 acc = {0.f, 0.f, 0.f, 0.f};
    for (int e = beg; e < end; ++e) {
        int2 rec = erec[e];
        float w = __int_as_float(rec.y);
        f32x4 v;
        if constexpr (sizeof(T) == 4) {
            v = *((const f32x4*)(h + (size_t)rec.x * DIM) + lane);
        } else {
            s16x4 bv = *((const s16x4*)(h + (size_t)rec.x * DIM) + lane);
            v[0] = bf2f(bv[0]); v[1] = bf2f(bv[1]); v[2] = bf2f(bv[2]); v[3] = bf2f(bv[3]);
        }
        acc += v * w;
    }
    acc *= rs_in[r * N_NODES + d];
    s16x4 o;
    o[0] = f2bf(acc[0]); o[1] = f2bf(acc[1]); o[2] = f2bf(acc[2]); o[3] = f2bf(acc[3]);
    *((s16x4*)(agg + (size_t)d * K_TOT + r * DIM) + lane) = o;
}

// ---------------- GEMM: out[M,128] = A[M,512](bf16) @ Wt^T + bias ------------
template <bool RELU, bool OUTBF>
__global__ __launch_bounds__(256, 2)
void gemm_kernel(const short* __restrict__ A, const short* __restrict__ Wt,
                 const float* __restrict__ bias, void* __restrict__ outv) {
    __shared__ short a_sh[128 * 72];   // [row][k], padded stride 72
    __shared__ short b_sh[128 * 72];   // [col][k], padded stride 72

    const int tid  = threadIdx.x;
    const int bm0  = blockIdx.x * BM;
    const int lane = tid & 63;
    const int wid  = tid >> 6;
    const int wm   = wid >> 1, wn = wid & 1;   // 2x2 waves of 64x64
    const int l15  = lane & 15, l4 = lane >> 4;

    f32x4 acc[4][4] = {};

    for (int kk = 0; kk < K_TOT; kk += BK) {
        __syncthreads();
#pragma unroll
        for (int j = 0; j < 4; ++j) {
            int c = tid + 256 * j;
            int row = c >> 3, ku = c & 7;
            *(short8*)&a_sh[row * 72 + ku * 8] =
                *(const short8*)(A + (size_t)(bm0 + row) * K_TOT + kk + ku * 8);
        }
#pragma unroll
        for (int j = 0; j < 4; ++j) {
            int c = tid + 256 * j;
            int col = c >> 3, ku = c & 7;
            *(short8*)&b_sh[col * 72 + ku * 8] =
                *(const short8*)(Wt + (size_t)col * K_TOT + kk + ku * 8);
        }
        __syncthreads();
#pragma unroll
        for (int ki = 0; ki < 2; ++ki) {
            short8 a[4], b[4];
            int ku = ki * 4 + l4;
#pragma unroll
            for (int f = 0; f < 4; ++f) {
                int row = wm * 64 + f * 16 + l15;
                a[f] = *(const short8*)&a_sh[row * 72 + ku * 8];
                int col = wn * 64 + f * 16 + l15;
                b[f] = *(const short8*)&b_sh[col * 72 + ku * 8];
            }
#pragma unroll
            for (int fm = 0; fm < 4; ++fm)
#pragma unroll
                for (int fn = 0; fn < 4; ++fn)
                    acc[fm][fn] = __builtin_amdgcn_mfma_f32_16x16x32_bf16(
                        a[fm], b[fn], acc[fm][fn], 0, 0, 0);
        }
    }

    // epilogue: D mapping col = lane&15, row = (lane>>4)*4 + reg
#pragma unroll
    for (int fn = 0; fn < 4; ++fn) {
        int col = wn * 64 + fn * 16 + l15;
        float bi = bias[col];
#pragma unroll
        for (int fm = 0; fm < 4; ++fm) {
            int row0 = bm0 + wm * 64 + fm * 16 + l4 * 4;
#pragma unroll
            for (int rr = 0; rr < 4; ++rr) {
                int row = row0 + rr;
                if (row < N_NODES) {
                    float v = acc[fm][fn][rr] + bi;
                    if (RELU) v = fmaxf(v, 0.f);
                    if (OUTBF) ((short*)outv)[(size_t)row * DIM + col] = f2bf(v);
                    else       ((float*)outv)[(size_t)row * DIM + col] = v;
                }
            }
        }
    }
}

// ---------------- launcher ----------------
extern "C" void kernel_launch(void* const* d_in, const int* in_sizes, int n_in,
                              void* d_out, int out_size, void* d_ws, size_t ws_size,
                              hipStream_t stream) {
    const float* x    = (const float*)d_in[0];
    const int*   esrc = (const int*)  d_in[1];
    const int*   edst = (const int*)  d_in[2];
    const float* W1   = (const float*)d_in[3];
    const float* b1   = (const float*)d_in[4];
    const float* W2   = (const float*)d_in[5];
    const float* b2   = (const float*)d_in[6];
    float* out = (float*)d_out;
    char*  ws  = (char*)d_ws;

    // workspace layout (bytes), ~84.3 MB total:
    float* rs      = (float*)ws;                    // rs_out[R*N] + rs_in[R*N]
    float* rs_out  = rs;
    float* rs_in   = rs + R_REL * N_NODES;
    float* bias1   = (float*)(ws + 1600000);
    float* bias2   = (float*)(ws + 1600512);
    short* Wt1     = (short*)(ws + 1601024);        // 131,072
    short* Wt2     = (short*)(ws + 1732096);        // 131,072 -> 1,863,168
    short* h       = (short*)(ws + 1863168);        // bf16 [N][128] 12,800,000 -> 14,663,168
    short* agg     = (short*)(ws + 14663168);       // bf16 [M_PAD][512] 51,249,152 -> 65,912,320
    int*   cnt_src = (int*)  (ws + 65912320);       // [NC][NB] 6,400,000 -> 72,312,320
    int*   cnt_dst = (int*)  (ws + 72312320);       // [NC][NB] 6,400,000 -> 78,712,320
    int*   rowptr  = (int*)  (ws + 78712320);       // 800,064 -> 79,512,384
    int*   parts   = (int*)  (ws + 79512384);       // 4,096   -> 79,516,480
    int2*  erec    = (int2*) (ws + 79516544);       // 4,800,000 -> 84,316,544

    // zero the two histogram arrays (contiguous 12.8 MB)
    hipMemsetAsync(cnt_src, 0, 2 * 6400000, stream);

    const int e_blk = (E_TOT + 255) / 256;          // 2344
    hist_edges<<<e_blk, 256, 0, stream>>>(esrc, edst, cnt_src, cnt_dst);

    const int nb_blk = (NB + 255) / 256;            // 782
    finalize_deg<<<nb_blk, 256, 0, stream>>>(cnt_src, cnt_dst, rs_out, rs_in);

    scan1<<<nb_blk, 256, 0, stream>>>(cnt_dst, rowptr, parts);
    scan2<<<1, 1024, 0, stream>>>(parts, nb_blk);
    scan3<<<nb_blk, 256, 0, stream>>>(rowptr, parts, cnt_dst);

    fill_csr<<<e_blk, 256, 0, stream>>>(esrc, edst, rowptr, cnt_dst, rs_out, erec);

    prep_w<<<(2 * DIM * K_TOT) / 256, 256, 0, stream>>>(W1, b1, W2, b2, Wt1, Wt2, bias1, bias2);

    const int gat_blocks = (NB * 32) / 256;         // 25,000
    const int gemm_blocks = M_PAD / BM;             // 391

    // ---- layer 1 ----
    gather_edges<float><<<gat_blocks, 256, 0, stream>>>(rowptr, erec, rs_in, x, agg);
    gemm_kernel<true, true><<<gemm_blocks, 256, 0, stream>>>(agg, Wt1, bias1, h);

    // ---- layer 2 ----
    gather_edges<short><<<gat_blocks, 256, 0, stream>>>(rowptr, erec, rs_in, h, agg);
    gemm_kernel<false, false><<<gemm_blocks, 256, 0, stream>>>(agg, Wt2, bias2, out);
}

// Round 5
// 245.676 us; speedup vs baseline: 8.8620x; 1.0761x over previous
//
#include <hip/hip_runtime.h>
#include <hip/hip_bf16.h>
#include <stdint.h>

// Problem constants (from reference)
#define N_NODES 50000
#define R_REL   4
#define E_EDGES 150000
#define E_TOT   600000      // R * E
#define DIM     128
#define K_TOT   512         // R * DIM
#define M_PAD   50048       // 391 * 128  (ceil(N/128)*128)
#define NB      200000      // N * R buckets
#define NC      8           // histogram privatization copies (~per-XCD)
#define BM      128
#define BK      64

typedef __attribute__((ext_vector_type(4))) float f32x4;
typedef __attribute__((ext_vector_type(8))) short short8;
typedef __attribute__((ext_vector_type(4))) short s16x4;

__device__ __forceinline__ short f2bf(float f) {
    union { float f; unsigned u; } x{f};
    unsigned r = (x.u + 0x7fffu + ((x.u >> 16) & 1u)) >> 16;
    return (short)r;
}
__device__ __forceinline__ float bf2f(short s) {
    union { unsigned u; float f; } x;
    x.u = ((unsigned)(unsigned short)s) << 16;
    return x.f;
}

// ---------------- edge histograms (privatized 8-way by blockIdx&7 ~ XCD) ----
__global__ void hist_edges(const int* __restrict__ src, const int* __restrict__ dst,
                           int* __restrict__ cnt_src, int* __restrict__ cnt_dst) {
    int i = blockIdx.x * 256 + threadIdx.x;
    if (i >= E_TOT) return;
    int c = blockIdx.x & (NC - 1);
    int r = i / E_EDGES;
    atomicAdd(&cnt_src[c * NB + src[i] * 4 + r], 1);
    atomicAdd(&cnt_dst[c * NB + dst[i] * 4 + r], 1);
}

// ---------------- scan1 (fused degree finalize): per-block exclusive scan ---
__global__ void scan1(const int* __restrict__ cnt_src, const int* __restrict__ cnt_dst,
                      float* __restrict__ rs_out, float* __restrict__ rs_in,
                      int* __restrict__ row_ptr, int* __restrict__ partials) {
    __shared__ int sh[256];
    int tid = threadIdx.x;
    int i = blockIdx.x * 256 + tid;
    int v = 0;
    if (i < NB) {
        int s1 = 0;
#pragma unroll
        for (int c = 0; c < NC; ++c) { v += cnt_dst[c * NB + i]; s1 += cnt_src[c * NB + i]; }
        int node = i >> 2, r = i & 3;
        rs_out[r * N_NODES + node] = rsqrtf(fmaxf((float)s1, 1.0f));
        rs_in [r * N_NODES + node] = rsqrtf(fmaxf((float)v,  1.0f));
    }
    sh[tid] = v;
    __syncthreads();
#pragma unroll
    for (int off = 1; off < 256; off <<= 1) {
        int t2 = (tid >= off) ? sh[tid - off] : 0;
        __syncthreads();
        sh[tid] += t2;
        __syncthreads();
    }
    if (i < NB) row_ptr[i] = sh[tid] - v;      // exclusive
    if (tid == 255) partials[blockIdx.x] = sh[255];
}

__global__ void scan2(int* __restrict__ partials, int nb) {
    __shared__ int sh[1024];
    int tid = threadIdx.x;
    int v = (tid < nb) ? partials[tid] : 0;
    sh[tid] = v;
    __syncthreads();
    for (int off = 1; off < 1024; off <<= 1) {
        int t2 = (tid >= off) ? sh[tid - off] : 0;
        __syncthreads();
        sh[tid] += t2;
        __syncthreads();
    }
    if (tid < nb) partials[tid] = sh[tid] - v;  // exclusive
}

// scan3: add block offsets; convert per-copy counts -> per-copy exclusive bases
__global__ void scan3(int* __restrict__ row_ptr, const int* __restrict__ partials,
                      int* __restrict__ cnt_dst) {
    int i = blockIdx.x * 256 + threadIdx.x;
    if (i < NB) {
        row_ptr[i] += partials[i >> 8];
        int run = 0;
#pragma unroll
        for (int c = 0; c < NC; ++c) {
            int v = cnt_dst[c * NB + i];
            cnt_dst[c * NB + i] = run;
            run += v;
        }
    }
    if (i == 0) row_ptr[NB] = E_TOT;
}

// ---------------- fill CSR edge records {src, rs_out[r][src]} ----------------
__global__ void fill_csr(const int* __restrict__ src, const int* __restrict__ dst,
                         const int* __restrict__ row_ptr, int* __restrict__ base_cur,
                         const float* __restrict__ rs_out, int2* __restrict__ erec) {
    int i = blockIdx.x * 256 + threadIdx.x;
    if (i >= E_TOT) return;
    int c = blockIdx.x & (NC - 1);              // same mapping as hist_edges
    int r = i / E_EDGES;
    int s = src[i], d = dst[i];
    int b = d * 4 + r;
    int pos = row_ptr[b] + atomicAdd(&base_cur[c * NB + b], 1);
    int2 rec;
    rec.x = s;
    rec.y = __float_as_int(rs_out[r * N_NODES + s]);
    erec[pos] = rec;
}

// ---------------- weight prep (both layers in one launch) -------------------
__global__ void prep_w(const float* __restrict__ W1, const float* __restrict__ b1,
                       const float* __restrict__ W2, const float* __restrict__ b2,
                       short* __restrict__ Wt1, short* __restrict__ Wt2,
                       float* __restrict__ bias1, float* __restrict__ bias2) {
    int i = blockIdx.x * 256 + threadIdx.x;     // grid covers 2*DIM*K_TOT
    int layer = i >= DIM * K_TOT;
    int j = i - layer * DIM * K_TOT;
    const float* W = layer ? W2 : W1;
    short* Wt = layer ? Wt2 : Wt1;
    int o = j / K_TOT, k = j % K_TOT;           // k = r*128 + d
    Wt[j] = f2bf(W[(size_t)k * DIM + o]);
    if (j < DIM) {
        const float* b = layer ? b2 : b1;
        float* bias = layer ? bias2 : bias1;
        float s = 0.f;
        for (int r = 0; r < R_REL; ++r) s += b[r * DIM + j];
        bias[j] = s;
    }
}

// ---------------- gather: agg[d][r*128+:] = rs_in * sum_e w_e * h[src_e][:] (bf16 out)
// 32 lanes per (dst,r) pair. Edge records are prefetched lane-parallel
// (coalesced) and broadcast with __shfl -> no serial dependent-load chain.
template <typename T>
__global__ void gather_edges(const int* __restrict__ row_ptr, const int2* __restrict__ erec,
                             const float* __restrict__ rs_in, const T* __restrict__ h,
                             short* __restrict__ agg) {
    int t = blockIdx.x * blockDim.x + threadIdx.x;
    int pair = t >> 5;               // 32 lanes per (dst, r) pair
    if (pair >= NB) return;
    int lane = t & 31;
    int d = pair >> 2, r = pair & 3;
    int beg = row_ptr[pair], end = row_ptr[pair + 1];
    f32x4 acc = {0.f, 0.f, 0.f, 0.f};
    for (int base = beg; base < end; base += 32) {
        int m = end - base;
        if (m > 32) m = 32;
        int2 rec = {0, 0};
        if (lane < m) rec = erec[base + lane];
        int   rsrc = rec.x;
        float rw   = __int_as_float(rec.y);
        for (int e = 0; e < m; ++e) {
            int   s = __shfl(rsrc, e, 32);
            float w = __shfl(rw,   e, 32);
            f32x4 v;
            if constexpr (sizeof(T) == 4) {
                v = *((const f32x4*)(h + (size_t)s * DIM) + lane);
            } else {
                s16x4 bv = *((const s16x4*)(h + (size_t)s * DIM) + lane);
                v[0] = bf2f(bv[0]); v[1] = bf2f(bv[1]); v[2] = bf2f(bv[2]); v[3] = bf2f(bv[3]);
            }
            acc += v * w;
        }
    }
    acc *= rs_in[r * N_NODES + d];
    s16x4 o;
    o[0] = f2bf(acc[0]); o[1] = f2bf(acc[1]); o[2] = f2bf(acc[2]); o[3] = f2bf(acc[3]);
    *((s16x4*)(agg + (size_t)d * K_TOT + r * DIM) + lane) = o;
}

// ---------------- GEMM: out[M,128] = A[M,512](bf16) @ Wt^T + bias ------------
template <bool RELU, bool OUTBF>
__global__ __launch_bounds__(256, 2)
void gemm_kernel(const short* __restrict__ A, const short* __restrict__ Wt,
                 const float* __restrict__ bias, void* __restrict__ outv) {
    __shared__ short a_sh[128 * 72];   // [row][k], padded stride 72
    __shared__ short b_sh[128 * 72];   // [col][k], padded stride 72

    const int tid  = threadIdx.x;
    const int bm0  = blockIdx.x * BM;
    const int lane = tid & 63;
    const int wid  = tid >> 6;
    const int wm   = wid >> 1, wn = wid & 1;   // 2x2 waves of 64x64
    const int l15  = lane & 15, l4 = lane >> 4;

    f32x4 acc[4][4] = {};

    for (int kk = 0; kk < K_TOT; kk += BK) {
        __syncthreads();
#pragma unroll
        for (int j = 0; j < 4; ++j) {
            int c = tid + 256 * j;
            int row = c >> 3, ku = c & 7;
            *(short8*)&a_sh[row * 72 + ku * 8] =
                *(const short8*)(A + (size_t)(bm0 + row) * K_TOT + kk + ku * 8);
        }
#pragma unroll
        for (int j = 0; j < 4; ++j) {
            int c = tid + 256 * j;
            int col = c >> 3, ku = c & 7;
            *(short8*)&b_sh[col * 72 + ku * 8] =
                *(const short8*)(Wt + (size_t)col * K_TOT + kk + ku * 8);
        }
        __syncthreads();
#pragma unroll
        for (int ki = 0; ki < 2; ++ki) {
            short8 a[4], b[4];
            int ku = ki * 4 + l4;
#pragma unroll
            for (int f = 0; f < 4; ++f) {
                int row = wm * 64 + f * 16 + l15;
                a[f] = *(const short8*)&a_sh[row * 72 + ku * 8];
                int col = wn * 64 + f * 16 + l15;
                b[f] = *(const short8*)&b_sh[col * 72 + ku * 8];
            }
#pragma unroll
            for (int fm = 0; fm < 4; ++fm)
#pragma unroll
                for (int fn = 0; fn < 4; ++fn)
                    acc[fm][fn] = __builtin_amdgcn_mfma_f32_16x16x32_bf16(
                        a[fm], b[fn], acc[fm][fn], 0, 0, 0);
        }
    }

    // epilogue: D mapping col = lane&15, row = (lane>>4)*4 + reg
#pragma unroll
    for (int fn = 0; fn < 4; ++fn) {
        int col = wn * 64 + fn * 16 + l15;
        float bi = bias[col];
#pragma unroll
        for (int fm = 0; fm < 4; ++fm) {
            int row0 = bm0 + wm * 64 + fm * 16 + l4 * 4;
#pragma unroll
            for (int rr = 0; rr < 4; ++rr) {
                int row = row0 + rr;
                if (row < N_NODES) {
                    float v = acc[fm][fn][rr] + bi;
                    if (RELU) v = fmaxf(v, 0.f);
                    if (OUTBF) ((short*)outv)[(size_t)row * DIM + col] = f2bf(v);
                    else       ((float*)outv)[(size_t)row * DIM + col] = v;
                }
            }
        }
    }
}

// ---------------- launcher ----------------
extern "C" void kernel_launch(void* const* d_in, const int* in_sizes, int n_in,
                              void* d_out, int out_size, void* d_ws, size_t ws_size,
                              hipStream_t stream) {
    const float* x    = (const float*)d_in[0];
    const int*   esrc = (const int*)  d_in[1];
    const int*   edst = (const int*)  d_in[2];
    const float* W1   = (const float*)d_in[3];
    const float* b1   = (const float*)d_in[4];
    const float* W2   = (const float*)d_in[5];
    const float* b2   = (const float*)d_in[6];
    float* out = (float*)d_out;
    char*  ws  = (char*)d_ws;

    // workspace layout (bytes), ~84.3 MB total:
    float* rs      = (float*)ws;                    // rs_out[R*N] + rs_in[R*N]
    float* rs_out  = rs;
    float* rs_in   = rs + R_REL * N_NODES;
    float* bias1   = (float*)(ws + 1600000);
    float* bias2   = (float*)(ws + 1600512);
    short* Wt1     = (short*)(ws + 1601024);        // 131,072
    short* Wt2     = (short*)(ws + 1732096);        // 131,072 -> 1,863,168
    short* h       = (short*)(ws + 1863168);        // bf16 [N][128] 12,800,000 -> 14,663,168
    short* agg     = (short*)(ws + 14663168);       // bf16 [M_PAD][512] 51,249,152 -> 65,912,320
    int*   cnt_src = (int*)  (ws + 65912320);       // [NC][NB] 6,400,000 -> 72,312,320
    int*   cnt_dst = (int*)  (ws + 72312320);       // [NC][NB] 6,400,000 -> 78,712,320
    int*   rowptr  = (int*)  (ws + 78712320);       // 800,064 -> 79,512,384
    int*   parts   = (int*)  (ws + 79512384);       // 4,096   -> 79,516,480
    int2*  erec    = (int2*) (ws + 79516544);       // 4,800,000 -> 84,316,544

    // zero the two histogram arrays (contiguous 12.8 MB)
    hipMemsetAsync(cnt_src, 0, 2 * 6400000, stream);

    const int e_blk = (E_TOT + 255) / 256;          // 2344
    hist_edges<<<e_blk, 256, 0, stream>>>(esrc, edst, cnt_src, cnt_dst);

    const int nb_blk = (NB + 255) / 256;            // 782
    scan1<<<nb_blk, 256, 0, stream>>>(cnt_src, cnt_dst, rs_out, rs_in, rowptr, parts);
    scan2<<<1, 1024, 0, stream>>>(parts, nb_blk);
    scan3<<<nb_blk, 256, 0, stream>>>(rowptr, parts, cnt_dst);

    fill_csr<<<e_blk, 256, 0, stream>>>(esrc, edst, rowptr, cnt_dst, rs_out, erec);

    prep_w<<<(2 * DIM * K_TOT) / 256, 256, 0, stream>>>(W1, b1, W2, b2, Wt1, Wt2, bias1, bias2);

    const int gat_blocks = (NB * 32) / 256;         // 25,000
    const int gemm_blocks = M_PAD / BM;             // 391

    // ---- layer 1 ----
    gather_edges<float><<<gat_blocks, 256, 0, stream>>>(rowptr, erec, rs_in, x, agg);
    gemm_kernel<true, true><<<gemm_blocks, 256, 0, stream>>>(agg, Wt1, bias1, h);

    // ---- layer 2 ----
    gather_edges<short><<<gat_blocks, 256, 0, stream>>>(rowptr, erec, rs_in, h, agg);
    gemm_kernel<false, false><<<gemm_blocks, 256, 0, stream>>>(agg, Wt2, bias2, out);
}

// Round 6
// 245.566 us; speedup vs baseline: 8.8660x; 1.0004x over previous
//
#include <hip/hip_runtime.h>
#include <hip/hip_bf16.h>
#include <stdint.h>

// Problem constants (from reference)
#define N_NODES 50000
#define R_REL   4
#define E_EDGES 150000
#define E_TOT   600000      // R * E
#define DIM     128
#define K_TOT   512         // R * DIM
#define M_PAD   50048       // 391 * 128  (ceil(N/128)*128)
#define NB      200000      // N * R buckets
#define NC      8           // histogram privatization copies (~per-XCD)
#define BM      128
#define BK      64

typedef __attribute__((ext_vector_type(4))) float f32x4;
typedef __attribute__((ext_vector_type(8))) short short8;
typedef __attribute__((ext_vector_type(4))) short s16x4;

__device__ __forceinline__ short f2bf(float f) {
    union { float f; unsigned u; } x{f};
    unsigned r = (x.u + 0x7fffu + ((x.u >> 16) & 1u)) >> 16;
    return (short)r;
}
__device__ __forceinline__ float bf2f(short s) {
    union { unsigned u; float f; } x;
    x.u = ((unsigned)(unsigned short)s) << 16;
    return x.f;
}

// ---------------- edge histograms (privatized 8-way by blockIdx&7 ~ XCD) ----
__global__ void hist_edges(const int* __restrict__ src, const int* __restrict__ dst,
                           int* __restrict__ cnt_src, int* __restrict__ cnt_dst) {
    int i = blockIdx.x * 256 + threadIdx.x;
    if (i >= E_TOT) return;
    int c = blockIdx.x & (NC - 1);
    int r = i / E_EDGES;
    atomicAdd(&cnt_src[c * NB + src[i] * 4 + r], 1);
    atomicAdd(&cnt_dst[c * NB + dst[i] * 4 + r], 1);
}

// ---------------- scan1 (fused degree finalize): per-block exclusive scan ---
__global__ void scan1(const int* __restrict__ cnt_src, const int* __restrict__ cnt_dst,
                      float* __restrict__ rs_out, float* __restrict__ rs_in,
                      int* __restrict__ row_ptr, int* __restrict__ partials) {
    __shared__ int sh[256];
    int tid = threadIdx.x;
    int i = blockIdx.x * 256 + tid;
    int v = 0;
    if (i < NB) {
        int s1 = 0;
#pragma unroll
        for (int c = 0; c < NC; ++c) { v += cnt_dst[c * NB + i]; s1 += cnt_src[c * NB + i]; }
        int node = i >> 2, r = i & 3;
        rs_out[r * N_NODES + node] = rsqrtf(fmaxf((float)s1, 1.0f));
        rs_in [r * N_NODES + node] = rsqrtf(fmaxf((float)v,  1.0f));
    }
    sh[tid] = v;
    __syncthreads();
#pragma unroll
    for (int off = 1; off < 256; off <<= 1) {
        int t2 = (tid >= off) ? sh[tid - off] : 0;
        __syncthreads();
        sh[tid] += t2;
        __syncthreads();
    }
    if (i < NB) row_ptr[i] = sh[tid] - v;      // exclusive
    if (tid == 255) partials[blockIdx.x] = sh[255];
}

__global__ void scan2(int* __restrict__ partials, int nb) {
    __shared__ int sh[1024];
    int tid = threadIdx.x;
    int v = (tid < nb) ? partials[tid] : 0;
    sh[tid] = v;
    __syncthreads();
    for (int off = 1; off < 1024; off <<= 1) {
        int t2 = (tid >= off) ? sh[tid - off] : 0;
        __syncthreads();
        sh[tid] += t2;
        __syncthreads();
    }
    if (tid < nb) partials[tid] = sh[tid] - v;  // exclusive
}

// scan3: add block offsets; convert per-copy counts -> per-copy exclusive bases
__global__ void scan3(int* __restrict__ row_ptr, const int* __restrict__ partials,
                      int* __restrict__ cnt_dst) {
    int i = blockIdx.x * 256 + threadIdx.x;
    if (i < NB) {
        row_ptr[i] += partials[i >> 8];
        int run = 0;
#pragma unroll
        for (int c = 0; c < NC; ++c) {
            int v = cnt_dst[c * NB + i];
            cnt_dst[c * NB + i] = run;
            run += v;
        }
    }
    if (i == 0) row_ptr[NB] = E_TOT;
}

// ---------------- fill CSR edge records {src, rs_out[r][src]} ----------------
__global__ void fill_csr(const int* __restrict__ src, const int* __restrict__ dst,
                         const int* __restrict__ row_ptr, int* __restrict__ base_cur,
                         const float* __restrict__ rs_out, int2* __restrict__ erec) {
    int i = blockIdx.x * 256 + threadIdx.x;
    if (i >= E_TOT) return;
    int c = blockIdx.x & (NC - 1);              // same mapping as hist_edges
    int r = i / E_EDGES;
    int s = src[i], d = dst[i];
    int b = d * 4 + r;
    int pos = row_ptr[b] + atomicAdd(&base_cur[c * NB + b], 1);
    int2 rec;
    rec.x = s;
    rec.y = __float_as_int(rs_out[r * N_NODES + s]);
    erec[pos] = rec;
}

// ---------------- weight prep (both layers in one launch) -------------------
__global__ void prep_w(const float* __restrict__ W1, const float* __restrict__ b1,
                       const float* __restrict__ W2, const float* __restrict__ b2,
                       short* __restrict__ Wt1, short* __restrict__ Wt2,
                       float* __restrict__ bias1, float* __restrict__ bias2) {
    int i = blockIdx.x * 256 + threadIdx.x;     // grid covers 2*DIM*K_TOT
    int layer = i >= DIM * K_TOT;
    int j = i - layer * DIM * K_TOT;
    const float* W = layer ? W2 : W1;
    short* Wt = layer ? Wt2 : Wt1;
    int o = j / K_TOT, k = j % K_TOT;           // k = r*128 + d
    Wt[j] = f2bf(W[(size_t)k * DIM + o]);
    if (j < DIM) {
        const float* b = layer ? b2 : b1;
        float* bias = layer ? bias2 : bias1;
        float s = 0.f;
        for (int r = 0; r < R_REL; ++r) s += b[r * DIM + j];
        bias[j] = s;
    }
}

// ---------------- gather: agg[d][r*128+:] = rs_in * sum_e w_e * h[src_e][:] (bf16 out)
// 32 lanes per (dst,r) pair. Edge records prefetched lane-parallel + shuffle
// broadcast; h-row loads issued in chunks of 4 independent loads (predicated)
// so only ~1 L2/L3 latency is exposed per pair instead of 1 per edge.
template <typename T>
__global__ void gather_edges(const int* __restrict__ row_ptr, const int2* __restrict__ erec,
                             const float* __restrict__ rs_in, const T* __restrict__ h,
                             short* __restrict__ agg) {
    int t = blockIdx.x * blockDim.x + threadIdx.x;
    int pair = t >> 5;               // 32 lanes per (dst, r) pair
    if (pair >= NB) return;
    int lane = t & 31;
    int d = pair >> 2, r = pair & 3;
    int beg = row_ptr[pair], end = row_ptr[pair + 1];
    f32x4 acc = {0.f, 0.f, 0.f, 0.f};
    for (int base = beg; base < end; base += 32) {
        int m = end - base;
        if (m > 32) m = 32;
        int2 rec = {0, 0};
        if (lane < m) rec = erec[base + lane];
        int   rsrc = rec.x;
        float rw   = __int_as_float(rec.y);
        for (int e0 = 0; e0 < m; e0 += 4) {
            f32x4 v[4];
            // phase 1: up to 4 independent row loads (no acc dependency)
#pragma unroll
            for (int k = 0; k < 4; ++k) {
                int e = e0 + k;
                int s = __shfl(rsrc, (e < m) ? e : 0, 32);
                if (e < m) {
                    if constexpr (sizeof(T) == 4) {
                        v[k] = *((const f32x4*)(h + (size_t)s * DIM) + lane);
                    } else {
                        s16x4 bv = *((const s16x4*)(h + (size_t)s * DIM) + lane);
                        v[k][0] = bf2f(bv[0]); v[k][1] = bf2f(bv[1]);
                        v[k][2] = bf2f(bv[2]); v[k][3] = bf2f(bv[3]);
                    }
                }
            }
            // phase 2: FMAs
#pragma unroll
            for (int k = 0; k < 4; ++k) {
                int e = e0 + k;
                float wk = __shfl(rw, (e < m) ? e : 0, 32);
                if (e < m) acc += v[k] * wk;
            }
        }
    }
    acc *= rs_in[r * N_NODES + d];
    s16x4 o;
    o[0] = f2bf(acc[0]); o[1] = f2bf(acc[1]); o[2] = f2bf(acc[2]); o[3] = f2bf(acc[3]);
    *((s16x4*)(agg + (size_t)d * K_TOT + r * DIM) + lane) = o;
}

// ---------------- GEMM: out[M,128] = A[M,512](bf16) @ Wt^T + bias ------------
template <bool RELU, bool OUTBF>
__global__ __launch_bounds__(256, 2)
void gemm_kernel(const short* __restrict__ A, const short* __restrict__ Wt,
                 const float* __restrict__ bias, void* __restrict__ outv) {
    __shared__ short a_sh[128 * 72];   // [row][k], padded stride 72
    __shared__ short b_sh[128 * 72];   // [col][k], padded stride 72

    const int tid  = threadIdx.x;
    const int bm0  = blockIdx.x * BM;
    const int lane = tid & 63;
    const int wid  = tid >> 6;
    const int wm   = wid >> 1, wn = wid & 1;   // 2x2 waves of 64x64
    const int l15  = lane & 15, l4 = lane >> 4;

    f32x4 acc[4][4] = {};

    for (int kk = 0; kk < K_TOT; kk += BK) {
        __syncthreads();
#pragma unroll
        for (int j = 0; j < 4; ++j) {
            int c = tid + 256 * j;
            int row = c >> 3, ku = c & 7;
            *(short8*)&a_sh[row * 72 + ku * 8] =
                *(const short8*)(A + (size_t)(bm0 + row) * K_TOT + kk + ku * 8);
        }
#pragma unroll
        for (int j = 0; j < 4; ++j) {
            int c = tid + 256 * j;
            int col = c >> 3, ku = c & 7;
            *(short8*)&b_sh[col * 72 + ku * 8] =
                *(const short8*)(Wt + (size_t)col * K_TOT + kk + ku * 8);
        }
        __syncthreads();
#pragma unroll
        for (int ki = 0; ki < 2; ++ki) {
            short8 a[4], b[4];
            int ku = ki * 4 + l4;
#pragma unroll
            for (int f = 0; f < 4; ++f) {
                int row = wm * 64 + f * 16 + l15;
                a[f] = *(const short8*)&a_sh[row * 72 + ku * 8];
                int col = wn * 64 + f * 16 + l15;
                b[f] = *(const short8*)&b_sh[col * 72 + ku * 8];
            }
#pragma unroll
            for (int fm = 0; fm < 4; ++fm)
#pragma unroll
                for (int fn = 0; fn < 4; ++fn)
                    acc[fm][fn] = __builtin_amdgcn_mfma_f32_16x16x32_bf16(
                        a[fm], b[fn], acc[fm][fn], 0, 0, 0);
        }
    }

    // epilogue: D mapping col = lane&15, row = (lane>>4)*4 + reg
#pragma unroll
    for (int fn = 0; fn < 4; ++fn) {
        int col = wn * 64 + fn * 16 + l15;
        float bi = bias[col];
#pragma unroll
        for (int fm = 0; fm < 4; ++fm) {
            int row0 = bm0 + wm * 64 + fm * 16 + l4 * 4;
#pragma unroll
            for (int rr = 0; rr < 4; ++rr) {
                int row = row0 + rr;
                if (row < N_NODES) {
                    float v = acc[fm][fn][rr] + bi;
                    if (RELU) v = fmaxf(v, 0.f);
                    if (OUTBF) ((short*)outv)[(size_t)row * DIM + col] = f2bf(v);
                    else       ((float*)outv)[(size_t)row * DIM + col] = v;
                }
            }
        }
    }
}

// ---------------- launcher ----------------
extern "C" void kernel_launch(void* const* d_in, const int* in_sizes, int n_in,
                              void* d_out, int out_size, void* d_ws, size_t ws_size,
                              hipStream_t stream) {
    const float* x    = (const float*)d_in[0];
    const int*   esrc = (const int*)  d_in[1];
    const int*   edst = (const int*)  d_in[2];
    const float* W1   = (const float*)d_in[3];
    const float* b1   = (const float*)d_in[4];
    const float* W2   = (const float*)d_in[5];
    const float* b2   = (const float*)d_in[6];
    float* out = (float*)d_out;
    char*  ws  = (char*)d_ws;

    // workspace layout (bytes), ~84.3 MB total:
    float* rs      = (float*)ws;                    // rs_out[R*N] + rs_in[R*N]
    float* rs_out  = rs;
    float* rs_in   = rs + R_REL * N_NODES;
    float* bias1   = (float*)(ws + 1600000);
    float* bias2   = (float*)(ws + 1600512);
    short* Wt1     = (short*)(ws + 1601024);        // 131,072
    short* Wt2     = (short*)(ws + 1732096);        // 131,072 -> 1,863,168
    short* h       = (short*)(ws + 1863168);        // bf16 [N][128] 12,800,000 -> 14,663,168
    short* agg     = (short*)(ws + 14663168);       // bf16 [M_PAD][512] 51,249,152 -> 65,912,320
    int*   cnt_src = (int*)  (ws + 65912320);       // [NC][NB] 6,400,000 -> 72,312,320
    int*   cnt_dst = (int*)  (ws + 72312320);       // [NC][NB] 6,400,000 -> 78,712,320
    int*   rowptr  = (int*)  (ws + 78712320);       // 800,064 -> 79,512,384
    int*   parts   = (int*)  (ws + 79512384);       // 4,096   -> 79,516,480
    int2*  erec    = (int2*) (ws + 79516544);       // 4,800,000 -> 84,316,544

    // zero the two histogram arrays (contiguous 12.8 MB)
    hipMemsetAsync(cnt_src, 0, 2 * 6400000, stream);

    const int e_blk = (E_TOT + 255) / 256;          // 2344
    hist_edges<<<e_blk, 256, 0, stream>>>(esrc, edst, cnt_src, cnt_dst);

    const int nb_blk = (NB + 255) / 256;            // 782
    scan1<<<nb_blk, 256, 0, stream>>>(cnt_src, cnt_dst, rs_out, rs_in, rowptr, parts);
    scan2<<<1, 1024, 0, stream>>>(parts, nb_blk);
    scan3<<<nb_blk, 256, 0, stream>>>(rowptr, parts, cnt_dst);

    fill_csr<<<e_blk, 256, 0, stream>>>(esrc, edst, rowptr, cnt_dst, rs_out, erec);

    prep_w<<<(2 * DIM * K_TOT) / 256, 256, 0, stream>>>(W1, b1, W2, b2, Wt1, Wt2, bias1, bias2);

    const int gat_blocks = (NB * 32) / 256;         // 25,000
    const int gemm_blocks = M_PAD / BM;             // 391

    // ---- layer 1 ----
    gather_edges<float><<<gat_blocks, 256, 0, stream>>>(rowptr, erec, rs_in, x, agg);
    gemm_kernel<true, true><<<gemm_blocks, 256, 0, stream>>>(agg, Wt1, bias1, h);

    // ---- layer 2 ----
    gather_edges<short><<<gat_blocks, 256, 0, stream>>>(rowptr, erec, rs_in, h, agg);
    gemm_kernel<false, false><<<gemm_blocks, 256, 0, stream>>>(agg, Wt2, bias2, out);
}